// Round 13
// baseline (72.245 us; speedup 1.0000x reference)
//
#include <hip/hip_runtime.h>

#define HID 768
#define NL  17
#define BB  64
#define TT  512

// ---- emis geometry ----
#define RB    32                 // rows per block
#define CK    128                // K-chunk (floats)
#define NCH   6                  // HID / CK
#define XTF   (RB * CK / 4)      // 1024 granules (16B) per x buffer
#define WTF   576                // w buffer granules: 544 real + 32 pad
#define XB(b) ((b) * XTF * 4)                    // float offset of x buf
#define WB(b) ((2 * XTF + (b) * WTF) * 4)        // float offset of w buf
#define SMEMF ((2 * XTF + 2 * WTF) * 4)          // 12800 floats = 51.2 KB

// ---- CRF scan geometry (unchanged from R12) ----
#define SEG  16
#define SLEN 32
#define QST  352

// ===========================================================================
// Kernel 1: emissions = outputs @ fc_w^T + fc_b   (32768x768 @ 768^T x 17)
// 128 thr (2 waves), 32 rows/block, grid 1024 (3 blocks/CU, 51.2 KB LDS).
// Register blocking R_T=4: thread (rowgrp=tid>>4, ks=tid&15) owns 4 rows x
// 8 K-cols {ks, ks+16} per chunk -> 544 FMA per 42 ds_read (vs 3.8:1 before;
// R8-R11 plateau was LDS-issue-bound on w reads). w reads are 4-way lane-
// broadcast; x reads XOR-swizzled via pre-swizzled gload source (rule #21),
// granule sets {ks}^key and {ks+16}^key have mixed parity -> all 32 banks.
// Staging: R11's counted-vmcnt gload_lds, uniform 13 loads/thread/chunk
// (8 x + 4 w + 1 clamped duplicate for w granules 512..543; dest pad 32 gr).
// 16-way K-split reduced once per block via bank-staggered LDS (stride 660).
// ===========================================================================
__device__ __forceinline__ void gload16(const float* g, float* l) {
    __builtin_amdgcn_global_load_lds(
        (const __attribute__((address_space(1))) float*)g,
        (__attribute__((address_space(3))) float*)l, 16, 0, 0);
}

__global__ __launch_bounds__(128) void emis_kernel(const float* __restrict__ x,
                                                   const float* __restrict__ w,
                                                   const float* __restrict__ bias,
                                                   float* __restrict__ y) {
    __shared__ float smem[SMEMF];

    const int tid = threadIdx.x;
    const int wub = tid & ~63;                 // wave-uniform granule base
    const size_t rowbase = (size_t)blockIdx.x * RB;

#define XSTAGE(buf, c)                                                        \
    {                                                                         \
        _Pragma("unroll")                                                     \
        for (int i = 0; i < 8; ++i) {          /* x: granules tid+128i */     \
            const int gx = tid + 128 * i;                                     \
            const int rr = gx >> 5, cg = gx & 31;                             \
            gload16(x + (rowbase + rr) * HID + (c) * CK + ((cg ^ (rr & 15)) << 2), \
                    &smem[XB(buf) + ((wub + 128 * i) << 2)]);                 \
        }                                                                     \
        _Pragma("unroll")                                                     \
        for (int i = 0; i < 4; ++i) {          /* w: granules tid+128i */     \
            const int gw = tid + 128 * i;                                     \
            gload16(w + (gw >> 5) * HID + (c) * CK + ((gw & 31) << 2),        \
                    &smem[WB(buf) + ((wub + 128 * i) << 2)]);                 \
        }                                                                     \
        /* w tail granules 512..543: clamped source, pad absorbs lanes>=32 */ \
        gload16(w + 16 * HID + (c) * CK + ((tid & 31) << 2),                  \
                &smem[WB(buf) + (512 << 2)]);                                 \
        __builtin_amdgcn_sched_barrier(0);                                    \
    }

    XSTAGE(0, 0) XSTAGE(1, 1)                  // 2-deep prologue (26 loads)

    float acc[4][NL];
#pragma unroll
    for (int i = 0; i < 4; ++i)
#pragma unroll
        for (int k = 0; k < NL; ++k) acc[i][k] = 0.f;

    const int rowgrp = tid >> 4;               // 0..7
    const int ks     = tid & 15;               // col slot

    asm volatile("s_waitcnt vmcnt(13)" ::: "memory");   // chunk 0 landed
    __builtin_amdgcn_s_barrier();
    asm volatile("" ::: "memory");

#define COMPUTE(buf)                                                          \
    {                                                                         \
        float4 xf[4][2];                                                      \
        _Pragma("unroll")                                                     \
        for (int i = 0; i < 4; ++i) {                                         \
            const int R = rowgrp * 4 + i;                                     \
            const int g0 = (R << 5) + (ks ^ (R & 15));                        \
            xf[i][0] = *reinterpret_cast<const float4*>(&smem[XB(buf) + (g0 << 2)]); \
            xf[i][1] = *reinterpret_cast<const float4*>(&smem[XB(buf) + ((g0 + 16) << 2)]); \
        }                                                                     \
        _Pragma("unroll")                                                     \
        for (int k = 0; k < NL; ++k) {                                        \
            const float4 w0 = *reinterpret_cast<const float4*>(               \
                &smem[WB(buf) + (((k << 5) + ks) << 2)]);                     \
            const float4 w1 = *reinterpret_cast<const float4*>(               \
                &smem[WB(buf) + (((k << 5) + ks + 16) << 2)]);                \
            _Pragma("unroll")                                                 \
            for (int i = 0; i < 4; ++i) {                                     \
                float s0 = fmaf(xf[i][0].x, w0.x, acc[i][k]);                 \
                float s1 = xf[i][0].y * w0.y;                                 \
                s0 = fmaf(xf[i][0].z, w0.z, s0);                              \
                s1 = fmaf(xf[i][0].w, w0.w, s1);                              \
                s0 = fmaf(xf[i][1].x, w1.x, s0);                              \
                s1 = fmaf(xf[i][1].y, w1.y, s1);                              \
                s0 = fmaf(xf[i][1].z, w1.z, s0);                              \
                s1 = fmaf(xf[i][1].w, w1.w, s1);                              \
                acc[i][k] = s0 + s1;                                          \
            }                                                                 \
        }                                                                     \
    }

#define STEP(c, buf, nb, nc, VM)                                              \
    COMPUTE(buf)                                                              \
    asm volatile("s_waitcnt lgkmcnt(0)" ::: "memory");                        \
    __builtin_amdgcn_s_barrier();              /* readers of buf done */      \
    XSTAGE(nb, nc)                                                            \
    asm volatile("s_waitcnt vmcnt(" #VM ")" ::: "memory");                    \
    __builtin_amdgcn_s_barrier();                                             \
    asm volatile("" ::: "memory");

    STEP(0, 0, 0, 2, 13)                       // compute c0, stage c2
    STEP(1, 1, 1, 3, 13)
    STEP(2, 0, 0, 4, 13)
    STEP(3, 1, 1, 5, 13)

    COMPUTE(0)                                 // c4
    asm volatile("s_waitcnt lgkmcnt(0)" ::: "memory");
    __builtin_amdgcn_s_barrier();
    asm volatile("s_waitcnt vmcnt(0)" ::: "memory");   // c5 landed
    __builtin_amdgcn_s_barrier();
    asm volatile("" ::: "memory");

    COMPUTE(1)                                 // c5

#undef XSTAGE
#undef COMPUTE
#undef STEP

    // ---- split-16 reduce: pacc[ks][row][20], ks-stride 660 (bank stagger) ----
    __syncthreads();
#pragma unroll
    for (int i = 0; i < 4; ++i) {
        const int row = rowgrp * 4 + i;
        float* pb = &smem[ks * 660 + row * 20];
#pragma unroll
        for (int q = 0; q < 4; ++q) {
            float4 t;
            t.x = acc[i][4 * q + 0]; t.y = acc[i][4 * q + 1];
            t.z = acc[i][4 * q + 2]; t.w = acc[i][4 * q + 3];
            *reinterpret_cast<float4*>(pb + 4 * q) = t;
        }
        pb[16] = acc[i][16];
    }
    __syncthreads();

    for (int o = tid; o < RB * NL; o += 128) {
        const int row = o / NL, k = o - row * NL;
        float s = bias[k];
#pragma unroll
        for (int kk = 0; kk < 16; ++kk) s += smem[kk * 660 + row * 20 + k];
        y[rowbase * NL + o] = s;
    }
}

// ===========================================================================
// Kernel 2a: CRF segment scan — UNCHANGED from R12.
// ===========================================================================
__global__ __launch_bounds__(64) void crf_scan_kernel(const float* __restrict__ emis,
                                                      const float* __restrict__ tr_,
                                                      const int* __restrict__ mask,
                                                      float* __restrict__ ws) {
    __shared__ float QT[2][18][20];

    const int bs = blockIdx.x;
    const int b  = bs >> 4;
    const int s  = bs & 15;
    const int l  = threadIdx.x;
    const float* eb = emis + (size_t)b * TT * NL;

    int lenp = 0;
#pragma unroll
    for (int m = 0; m < 8; ++m) lenp += (mask[b * TT + l + 64 * m] != 0);
#pragma unroll
    for (int off = 32; off; off >>= 1) lenp += __shfl_down(lenp, off);
    const int len = __shfl(lenp, 0);

    const int t0    = 1 + SLEN * s;
    const int tend  = min(t0 + SLEN, len);
    const int trips = (tend > t0) ? (tend - t0) : 0;

    const bool act = (l < 51);
    const int  i   = act ? (l / 3) : 0;
    const int  m   = act ? (l - 3 * (l / 3)) : 0;
    const int  j0  = 6 * m;

    if (act) {
#pragma unroll
        for (int jj = 0; jj < 6; ++jj)
            QT[0][j0 + jj][i] = (i == j0 + jj) ? 1.f : 0.f;
    }

    float at[17];
#pragma unroll
    for (int k = 0; k < 17; ++k) at[k] = __expf(tr_[k * NL + i]);

    float psc = 1.f;
    int   Mi  = 0;
    float emv = (trips > 0) ? eb[t0 * NL + i] : 0.f;
    int   t   = t0;

#define QSTEP(SRC, DST, TCUR)                                                 \
    {                                                                         \
        const float e_ = __expf(emv) * psc;  psc = 1.f;                       \
        const int tn_ = ((TCUR) + 1 < tend) ? ((TCUR) + 1) : (TT - 1);        \
        const float env_ = eb[tn_ * NL + i];                                  \
        float o[6];                                                           \
        _Pragma("unroll")                                                     \
        for (int jj = 0; jj < 6; ++jj) {                                      \
            const float* qr = &QT[SRC][j0 + jj][0];                           \
            const float4 a0 = *reinterpret_cast<const float4*>(qr);           \
            const float4 a1 = *reinterpret_cast<const float4*>(qr + 4);       \
            const float4 a2 = *reinterpret_cast<const float4*>(qr + 8);       \
            const float4 a3 = *reinterpret_cast<const float4*>(qr + 12);      \
            const float aL  = qr[16];                                         \
            float u0 = at[0] * a0.x, u1 = at[1] * a0.y;                       \
            float u2 = at[2] * a0.z, u3 = at[3] * a0.w;                       \
            u0 = fmaf(at[4],  a1.x, u0); u1 = fmaf(at[5],  a1.y, u1);         \
            u2 = fmaf(at[6],  a1.z, u2); u3 = fmaf(at[7],  a1.w, u3);         \
            u0 = fmaf(at[8],  a2.x, u0); u1 = fmaf(at[9],  a2.y, u1);         \
            u2 = fmaf(at[10], a2.z, u2); u3 = fmaf(at[11], a2.w, u3);         \
            u0 = fmaf(at[12], a3.x, u0); u1 = fmaf(at[13], a3.y, u1);         \
            u2 = fmaf(at[14], a3.z, u2); u3 = fmaf(at[15], a3.w, u3);         \
            u0 = fmaf(at[16], aL,   u0);                                      \
            o[jj] = (u0 + u1) + (u2 + u3);                                    \
        }                                                                     \
        if (act) {                                                            \
            _Pragma("unroll")                                                 \
            for (int jj = 0; jj < 6; ++jj)                                    \
                QT[DST][j0 + jj][i] = e_ * o[jj];                             \
        }                                                                     \
        emv = env_;                                                           \
    }

    for (int pp = 0; pp < (trips >> 1); ++pp) {
        QSTEP(0, 1, t)
        QSTEP(1, 0, t + 1)
        t += 2;
        const float q00 = QT[0][0][0];
        const int E = (int)((__float_as_uint(q00) >> 23) & 0xff) - 127;
        Mi += E;
        psc = __builtin_amdgcn_ldexpf(1.f, -E);
    }
    int sbuf = 0;
    if (trips & 1) { QSTEP(0, 1, t) sbuf = 1; }
#undef QSTEP

    if (act) {
        float* dst = ws + (size_t)bs * QST + i * 20;
#pragma unroll
        for (int jj = 0; jj < 6; ++jj) {
            const int j = j0 + jj;
            if (j < 17) dst[j] = psc * QT[sbuf][j][i];
        }
    }
    if (l == 0) ws[(size_t)bs * QST + 340] = (float)Mi;
}

// ===========================================================================
// Kernel 2b: combine — UNCHANGED from R12.
// ===========================================================================
__device__ __forceinline__ float bcast(float v, int i) {
    return __uint_as_float(__builtin_amdgcn_readlane(__float_as_uint(v), i));
}

__global__ __launch_bounds__(64) void crf_combine_kernel(const float* __restrict__ emis,
                                                         const float* __restrict__ st_,
                                                         const float* __restrict__ en_,
                                                         const float* __restrict__ tr_,
                                                         const int* __restrict__ labels,
                                                         const int* __restrict__ mask,
                                                         const float* __restrict__ ws,
                                                         float* __restrict__ llh) {
    const int b = blockIdx.x;
    const int l = threadIdx.x;
    const float* eb = emis + (size_t)b * TT * NL;
    const int*   lb = labels + b * TT;

    int lenp = 0;
#pragma unroll
    for (int m = 0; m < 8; ++m) lenp += (mask[b * TT + l + 64 * m] != 0);
#pragma unroll
    for (int off = 32; off; off >>= 1) lenp += __shfl_down(lenp, off);
    const int len = __shfl(lenp, 0);

    float np = 0.f;
#pragma unroll
    for (int m = 0; m < 8; ++m) {
        const int t = l + 64 * m;
        int tag = lb[t]; if ((unsigned)tag >= NL) tag = 0;
        if (t < len) {
            if (t == 0) {
                np += st_[tag] + eb[tag];
            } else {
                int tp = lb[t - 1]; if ((unsigned)tp >= NL) tp = 0;
                np += tr_[tp * NL + tag] + eb[t * NL + tag];
            }
            if (t == len - 1) np += en_[tag];
        }
    }
#pragma unroll
    for (int off = 32; off; off >>= 1) np += __shfl_down(np, off);
    const float num = __shfl(np, 0);

    const bool act = (l < NL);
    const int  j   = act ? l : 0;

    float p  = act ? __expf(st_[j] + eb[j]) : 0.f;
    int   Mi = 0;

    for (int s = 0; s < SEG; ++s) {
        const float* qs = ws + (size_t)(b * SEG + s) * QST;
        const float* qr = qs + j * 20;
        const float4 a0 = *reinterpret_cast<const float4*>(qr);
        const float4 a1 = *reinterpret_cast<const float4*>(qr + 4);
        const float4 a2 = *reinterpret_cast<const float4*>(qr + 8);
        const float4 a3 = *reinterpret_cast<const float4*>(qr + 12);
        const float  aL = qr[16];
        const float  Msc = qs[340];

        float u0 = a0.x * bcast(p, 0),  u1 = a0.y * bcast(p, 1);
        float u2 = a0.z * bcast(p, 2),  u3 = a0.w * bcast(p, 3);
        u0 = fmaf(a1.x, bcast(p, 4),  u0); u1 = fmaf(a1.y, bcast(p, 5),  u1);
        u2 = fmaf(a1.z, bcast(p, 6),  u2); u3 = fmaf(a1.w, bcast(p, 7),  u3);
        u0 = fmaf(a2.x, bcast(p, 8),  u0); u1 = fmaf(a2.y, bcast(p, 9),  u1);
        u2 = fmaf(a2.z, bcast(p, 10), u2); u3 = fmaf(a2.w, bcast(p, 11), u3);
        u0 = fmaf(a3.x, bcast(p, 12), u0); u1 = fmaf(a3.y, bcast(p, 13), u1);
        u2 = fmaf(a3.z, bcast(p, 14), u2); u3 = fmaf(a3.w, bcast(p, 15), u3);
        u0 = fmaf(aL,   bcast(p, 16), u0);
        p = act ? ((u0 + u1) + (u2 + u3)) : 0.f;
        Mi += (int)Msc;

        const unsigned pb = (unsigned)__builtin_amdgcn_readlane((int)__float_as_uint(p), 0);
        const int e = (int)((pb >> 23) & 0xff) - 127;
        Mi += e;
        p = __builtin_amdgcn_ldexpf(p, -e);
    }

    float v = act ? p * __expf(en_[j]) : 0.f;
#pragma unroll
    for (int off = 32; off; off >>= 1) v += __shfl_down(v, off);

    if (l == 0) {
        const float denom = (float)Mi * 0.6931471805599453f + __logf(v);
        llh[b] = num - denom;
    }
}

// ===========================================================================
// Kernel 3: loss = -mean(llh)
// ===========================================================================
__global__ __launch_bounds__(64) void loss_kernel(const float* __restrict__ llh,
                                                  float* __restrict__ loss) {
    float v = llh[threadIdx.x];
#pragma unroll
    for (int off = 32; off; off >>= 1) v += __shfl_down(v, off);
    if (threadIdx.x == 0) loss[0] = -(v * (1.0f / BB));
}

// ===========================================================================
extern "C" void kernel_launch(void* const* d_in, const int* in_sizes, int n_in,
                              void* d_out, int out_size, void* d_ws, size_t ws_size,
                              hipStream_t stream) {
    const float* outputs = (const float*)d_in[0];
    const float* fc_w    = (const float*)d_in[1];
    const float* fc_b    = (const float*)d_in[2];
    const float* start_t = (const float*)d_in[3];
    const float* end_t   = (const float*)d_in[4];
    const float* trans   = (const float*)d_in[5];
    const int*   labels  = (const int*)d_in[6];
    const int*   mask    = (const int*)d_in[7];

    float* emis = (float*)d_out;
    float* loss = emis + (size_t)BB * TT * NL;
    float* ws   = (float*)d_ws;
    float* llh  = ws + (size_t)BB * SEG * QST;

    emis_kernel<<<(BB * TT) / RB, 128, 0, stream>>>(outputs, fc_w, fc_b, emis);
    crf_scan_kernel<<<BB * SEG, 64, 0, stream>>>(emis, trans, mask, ws);
    crf_combine_kernel<<<BB, 64, 0, stream>>>(emis, start_t, end_t, trans,
                                              labels, mask, ws, llh);
    loss_kernel<<<1, 64, 0, stream>>>(llh, loss);
}